// Round 8
// baseline (255.912 us; speedup 1.0000x reference)
//
#include <hip/hip_runtime.h>

#define NTHREADS 256

typedef float v2f __attribute__((ext_vector_type(2)));

__device__ __forceinline__ int reflect128(int p) {
    p = (p < 0) ? (-p - 1) : p;
    p = (p >= 128) ? (255 - p) : p;
    return p;
}

// Per output phase j: 3 consecutive nonzero taps out of 5.
// cc0/cs0 apply to the G0-pair source (Yl or lh), cc1/cs1 to the G1-pair (hl or hh).
// TWO copies: __constant__ for runtime (per-lane jc) indexing; constexpr for the
// unrolled Phase-C (rule #20: __constant__ is not compile-time foldable -> round-6 spill).
__constant__ int   cs0[4] = {2, 1, 1, 0};
__constant__ int   cs1[4] = {1, 2, 0, 1};
__constant__ float cc0[4][3] = {
    { 0.760272369066126f, -0.0883294244510729f,  0.0351638365171441f},
    { 0.233890320607236f,  0.587518297723561f,  -0.114301837144249f},
    {-0.114301837144249f,  0.587518297723561f,   0.233890320607236f},
    { 0.0351638365171441f, -0.0883294244510729f, 0.760272369066126f}};
__constant__ float cc1[4][3] = {
    { 0.233890320607236f,  0.587518297723561f,  -0.114301837144249f},
    {-0.760272369066126f,  0.0883294244510729f, -0.0351638365171441f},
    {-0.0351638365171441f, 0.0883294244510729f, -0.760272369066126f},
    {-0.114301837144249f,  0.587518297723561f,   0.233890320607236f}};

static constexpr int   kcs0[4] = {2, 1, 1, 0};
static constexpr int   kcs1[4] = {1, 2, 0, 1};
static constexpr float kcc0[4][3] = {
    { 0.760272369066126f, -0.0883294244510729f,  0.0351638365171441f},
    { 0.233890320607236f,  0.587518297723561f,  -0.114301837144249f},
    {-0.114301837144249f,  0.587518297723561f,   0.233890320607236f},
    { 0.0351638365171441f, -0.0883294244510729f, 0.760272369066126f}};
static constexpr float kcc1[4][3] = {
    { 0.233890320607236f,  0.587518297723561f,  -0.114301837144249f},
    {-0.760272369066126f,  0.0883294244510729f, -0.0351638365171441f},
    {-0.0351638365171441f, 0.0883294244510729f, -0.760272369066126f},
    {-0.114301837144249f,  0.587518297723561f,   0.233890320607236f}};

// Barrier-free per-wave tiles. hint 4 -> VGPR cap 128 (hint 8 forced 32-VGPR spill
// catastrophe in round 4; live set here ~70).
__global__ __launch_bounds__(NTHREADS, 4)
void dtcwt_inv_kernel(const float* __restrict__ Yl,
                      const float* __restrict__ Yhr,
                      const float* __restrict__ Yhi,
                      float* __restrict__ out)
{
    const int tid  = threadIdx.x;
    const int lane = tid & 63;
    const int g    = tid >> 6;      // wave id = 16-row output strip

    // XCD-aware swizzle (FETCH 224->66 MB). Each XCD gets a contiguous run of
    // gidx = whole planes, so a plane's 16 tiles share one L2.
    const int bid  = blockIdx.x;
    const int perx = gridDim.x >> 3;               // blocks per XCD (grid % 8 == 0)
    const int gidx = (bid & 7) * perx + (bid >> 3);
    const int plane = gidx >> 4;                   // 0..511
    const int tile  = gidx & 15;
    const int ct = tile & 3;                       // col tile 0..3
    const int rt = tile >> 2;                      // row tile 0..3

    const int OR0 = rt * 64, OC0 = ct * 64;
    const int i0r = OR0 >> 2, i0c = OC0 >> 2;
    const int yrb = 2 * i0r - 4;    // raw first y row of the 40-row block window (even)
    const int icb = 2 * i0c - 4;    // raw first input col of the 40-col window (even)

    const float* yl = Yl + (size_t)plane * (128 * 128);
    const float* hr = Yhr + (size_t)plane * 6 * 4096;
    const float* hi = Yhi + (size_t)plane * 6 * 4096;

    // Per-WAVE LDS slices (no __syncthreads anywhere):
    //   wP[k][u] = (Yl, Lh), wQ[k][u] = (Hl, Hh); k = y-row t - (8g+1), k in [0,14).
    // 2 arrays x 4 waves x 14 x 40 x 8 B = 35.8 KB -> 4 blocks/CU.
    __shared__ v2f sP[4][14][40];
    __shared__ v2f sQ[4][14][40];
    v2f (*wP)[40] = sP[g];
    v2f (*wQ)[40] = sQ[g];

    const float RS2 = 0.70710678118654752440f;  // 1/sqrt(2)

    // ---- A1: this wave's 14 Yl rows (t = 8g+1 .. 8g+14), 40 cols, float4 loads.
    //      140 items = 14 rows x 10 col-quads; lanes take idx, idx+64, idx+128(<140).
    float4 f4[3];
    int trow[3], u4[3];
#pragma unroll
    for (int s = 0; s < 3; ++s) {
        const int idx = lane + s * 64;
        const int ok = (s < 2) | (idx < 140);
        const int idc = ok ? idx : 0;
        trow[s] = idc / 10;
        u4[s]   = idc - trow[s] * 10;
        const int t  = 8 * g + 1 + trow[s];
        const int ry = reflect128(yrb + t);
        const int cr0 = icb + 4 * u4[s];           // always 0 mod 4
        int base, rev;
        if (cr0 < 0)        { base = -cr0 - 4;  rev = 1; }   // fully-OOB quad -> reversed
        else if (cr0 > 124) { base = 252 - cr0; rev = 1; }
        else                { base = cr0;       rev = 0; }
        const float4 v = *(const float4*)(yl + ry * 128 + base);
        f4[s].x = rev ? v.w : v.x;
        f4[s].y = rev ? v.z : v.y;
        f4[s].z = rev ? v.y : v.z;
        f4[s].w = rev ? v.x : v.w;
        if (ok) {
            wP[trow[s]][4 * u4[s] + 0].x = f4[s].x;
            wP[trow[s]][4 * u4[s] + 1].x = f4[s].y;
            wP[trow[s]][4 * u4[s] + 2].x = f4[s].z;
            wP[trow[s]][4 * u4[s] + 3].x = f4[s].w;
        }
    }

    // ---- A2: this wave's c2q quads. Quad window: 8 rows (t2loc 0..7) x 20 cols.
    //      160 quads: lane, lane+64 always; lane+128 for lane<32.
    {
        const int q0 = lane, q1 = lane + 64;
        const int t2a = q0 / 20, u2a = q0 - t2a * 20;
        const int t2b = q1 / 20, u2b = q1 - t2b * 20;

        const int ara = i0r - 2 + 4 * g + t2a, aca = i0c - 2 + u2a;
        const int oobra = (ara < 0) | (ara >= 64);
        const int oobca = (aca < 0) | (aca >= 64);
        const int r2a = oobra ? ((ara < 0) ? (-ara - 1) : (127 - ara)) : ara;
        const int c2a = oobca ? ((aca < 0) ? (-aca - 1) : (127 - aca)) : aca;
        const int offa = r2a * 64 + c2a;

        const int arb = i0r - 2 + 4 * g + t2b, acb = i0c - 2 + u2b;
        const int oobrb = (arb < 0) | (arb >= 64);
        const int oobcb = (acb < 0) | (acb >= 64);
        const int r2b = oobrb ? ((arb < 0) ? (-arb - 1) : (127 - arb)) : arb;
        const int c2b = oobcb ? ((acb < 0) ? (-acb - 1) : (127 - acb)) : acb;
        const int offb = r2b * 64 + c2b;

        float Ra[6], Ia[6], Rb[6], Ib[6];
#pragma unroll
        for (int k = 0; k < 6; ++k) { Ra[k] = hr[k * 4096 + offa]; Ia[k] = hi[k * 4096 + offa]; }
#pragma unroll
        for (int k = 0; k < 6; ++k) { Rb[k] = hr[k * 4096 + offb]; Ib[k] = hi[k * 4096 + offb]; }

#pragma unroll
        for (int wq = 0; wq < 2; ++wq) {
            const float* R = (wq == 0) ? Ra : Rb;
            const float* I = (wq == 0) ? Ia : Ib;
            const int t2l = (wq == 0) ? t2a : t2b;
            const int u2  = (wq == 0) ? u2a : u2b;
            const int oobr = (wq == 0) ? oobra : oobrb;
            const int oobc = (wq == 0) ? oobca : oobcb;
#pragma unroll
            for (int dt = 0; dt < 2; ++dt) {
                const int tl = 2 * t2l + dt - 1;       // k index in [0,14)
                if (tl < 0 || tl >= 14) continue;
                const int p = dt ^ oobr;
#pragma unroll
                for (int du = 0; du < 2; ++du) {
                    const int q = du ^ oobc;
                    const float sA = (p & q) ? -RS2 : RS2;
                    const float sB = (p & (q ^ 1)) ? -RS2 : RS2;
                    float b0, b5, b2v, b3, b1, b4;
                    if (p == q) { b0 = R[0]; b5 = R[5]; b2v = R[2]; b3 = R[3]; b1 = R[1]; b4 = R[4]; }
                    else        { b0 = I[0]; b5 = I[5]; b2v = I[2]; b3 = I[3]; b1 = I[1]; b4 = I[4]; }
                    const int u = 2 * u2 + du;
                    wP[tl][u].y = sA * b0 + sB * b5;                 // Lh
                    v2f qv; qv.x = sA * b2v + sB * b3;               // Hl
                    qv.y = sA * b1 + sB * b4;                        // Hh
                    wQ[tl][u] = qv;
                }
            }
        }

        if (lane < 32) {                                 // third quad
            const int q2i = lane + 128;
            const int t2c = q2i / 20, u2c = q2i - t2c * 20;
            const int arc = i0r - 2 + 4 * g + t2c, acc_ = i0c - 2 + u2c;
            const int oobrc = (arc < 0) | (arc >= 64);
            const int oobcc = (acc_ < 0) | (acc_ >= 64);
            const int r2c = oobrc ? ((arc < 0) ? (-arc - 1) : (127 - arc)) : arc;
            const int c2c = oobcc ? ((acc_ < 0) ? (-acc_ - 1) : (127 - acc_)) : acc_;
            const int offc = r2c * 64 + c2c;
            float Rc[6], Ic[6];
#pragma unroll
            for (int k = 0; k < 6; ++k) { Rc[k] = hr[k * 4096 + offc]; Ic[k] = hi[k * 4096 + offc]; }
#pragma unroll
            for (int dt = 0; dt < 2; ++dt) {
                const int tl = 2 * t2c + dt - 1;
                if (tl < 0 || tl >= 14) continue;
                const int p = dt ^ oobrc;
#pragma unroll
                for (int du = 0; du < 2; ++du) {
                    const int q = du ^ oobcc;
                    const float sA = (p & q) ? -RS2 : RS2;
                    const float sB = (p & (q ^ 1)) ? -RS2 : RS2;
                    float b0, b5, b2v, b3, b1, b4;
                    if (p == q) { b0 = Rc[0]; b5 = Rc[5]; b2v = Rc[2]; b3 = Rc[3]; b1 = Rc[1]; b4 = Rc[4]; }
                    else        { b0 = Ic[0]; b5 = Ic[5]; b2v = Ic[2]; b3 = Ic[3]; b1 = Ic[1]; b4 = Ic[4]; }
                    const int u = 2 * u2c + du;
                    wP[tl][u].y = sA * b0 + sB * b5;
                    v2f qv; qv.x = sA * b2v + sB * b3;
                    qv.y = sA * b1 + sB * b4;
                    wQ[tl][u] = qv;
                }
            }
        }
    }

    // Wave-local fence: drain this wave's LDS writes, forbid compiler motion of
    // memory ops across it. No s_barrier -> zero cross-wave coupling.
    asm volatile("s_waitcnt lgkmcnt(0)" ::: "memory");
    __builtin_amdgcn_wave_barrier();

    // ---- Phase B (packed pk-fma) + C fused; wave-private, k = row directly. ----
    const int c  = lane;
    const int jc = c & 3;
    const int q2 = c >> 2;
    const float a0  = cc0[jc][0], a1  = cc0[jc][1], a2  = cc0[jc][2];
    const float b0w = cc1[jc][0], b1w = cc1[jc][1], b2w = cc1[jc][2];
    const int ub0 = 2 * q2 + (jc & 1) + 2 * cs0[jc];          // first G0 tap col (u)
    const int ub1 = 2 * q2 + ((jc & 1) ^ 1) + 2 * cs1[jc];    // first G1 tap col

    float y1v[14], y2v[14];         // scalar arrays (R3/R7-proven); v2f array spills (R6)
#pragma unroll
    for (int k = 0; k < 14; ++k) {
        const v2f acc = wP[k][ub0] * a0  + wP[k][ub0 + 2] * a1  + wP[k][ub0 + 4] * a2
                      + wQ[k][ub1] * b0w + wQ[k][ub1 + 2] * b1w + wQ[k][ub1 + 4] * b2w;
        y1v[k] = acc.x;
        y2v[k] = acc.y;
    }

    float* op = out + ((size_t)plane * 256 + OR0 + 16 * g) * 256 + OC0 + c;
#pragma unroll
    for (int j = 0; j < 4; ++j) {
        constexpr int P0c[4] = {0, 1, 0, 1};
        const int p0 = P0c[j], p1 = p0 ^ 1;
        const int r0 = p0 + 2 * kcs0[j];   // compile-time (constexpr tables)
        const int r1 = p1 + 2 * kcs1[j];
        const float d0 = kcc0[j][0], d1 = kcc0[j][1], d2 = kcc0[j][2];
        const float e0 = kcc1[j][0], e1 = kcc1[j][1], e2 = kcc1[j][2];
#pragma unroll
        for (int mm = 0; mm < 4; ++mm) {
            const int k0 = 2 * mm + r0 - 1;    // literal after unroll
            const int k1 = 2 * mm + r1 - 1;
            const float acc = y1v[k0] * d0 + y1v[k0 + 2] * d1 + y1v[k0 + 4] * d2
                            + y2v[k1] * e0 + y2v[k1 + 2] * e1 + y2v[k1 + 4] * e2;
            op[(size_t)(4 * mm + j) * 256] = acc;
        }
    }
}

extern "C" void kernel_launch(void* const* d_in, const int* in_sizes, int n_in,
                              void* d_out, int out_size, void* d_ws, size_t ws_size,
                              hipStream_t stream) {
    const float* Yl  = (const float*)d_in[0];
    const float* Yhr = (const float*)d_in[1];
    const float* Yhi = (const float*)d_in[2];
    float* out = (float*)d_out;

    const int planes = in_sizes[0] / (128 * 128);   // B*C = 512
    dim3 grid(planes * 16, 1, 1);
    dtcwt_inv_kernel<<<grid, NTHREADS, 0, stream>>>(Yl, Yhr, Yhi, out);
}